// Round 1
// 752.117 us; speedup vs baseline: 1.0208x; 1.0208x over previous
//
#include <hip/hip_runtime.h>
#include <cstdint>
#include <cstddef>

#define MROWS 200            // T*C real rows
#define PM    224            // padded rows: 14 frag-rows of 16 (>= 200)
#define KDIM  16384          // H*W
#define DDIM  8192           // hypervector dim
#define KSL   16             // k slices (grid.x)
#define KPER  (KDIM / KSL)   // 1024
#define BK    32

typedef __bf16 bf16x8 __attribute__((ext_vector_type(8)));
typedef float  f32x4  __attribute__((ext_vector_type(4)));

static __device__ __forceinline__ unsigned short f2bf_rne(float f) {
    unsigned int u = __float_as_uint(f);
    unsigned int r = (u + 0x7FFFu + ((u >> 16) & 1u)) >> 16;
    return (unsigned short)r;
}
static __device__ __forceinline__ float bf2f(unsigned short s) {
    return __uint_as_float(((unsigned int)s) << 16);
}

// async global->LDS, 16B per lane; LDS dest is wave-uniform base + lane*16
static __device__ __forceinline__ void gld_lds16(const unsigned short* g,
                                                 unsigned short* l) {
    __builtin_amdgcn_global_load_lds(
        (const __attribute__((address_space(1))) unsigned int*)g,
        (__attribute__((address_space(3))) unsigned int*)l, 16, 0, 0);
}

// ---------------------------------------------------------------------------
// Zero d_out (poisoned 0xAA before every timed launch).
// ---------------------------------------------------------------------------
__global__ __launch_bounds__(256) void zero_kernel(float* __restrict__ out) {
    out[blockIdx.x * 256 + threadIdx.x] = 0.f;
}

// ---------------------------------------------------------------------------
// Prep: split hist fp32 -> (hi, lo) bf16 planes ONCE (was recomputed per
// K-step per n-block = 64x redundant VALU). Rows [200,224) zero-padded.
// Granules (8 ushorts = 16 B) are stored PRE-SWIZZLED within each 64 B
// (32-k) chunk: stored[m][c][g] = orig[m][c][g ^ ((m>>1)&3)], so the gemm's
// global_load_lds destination stays LINEAR (rule #21) while the fragment
// read applies the same XOR -> A ds_read_b128 goes 8-way conflicted -> ~2-way.
// Replay-safe ws use: fully rewritten from inputs every launch.
// ---------------------------------------------------------------------------
__global__ __launch_bounds__(256) void prep_kernel(const float* __restrict__ hist,
                                                   unsigned short* __restrict__ ahi,
                                                   unsigned short* __restrict__ alo) {
    const int g  = blockIdx.x * 256 + threadIdx.x;   // granule id, < PM*2048
    const int m  = g >> 11;                          // 2048 granules per row
    const int gc = g & 2047;
    const int f  = (m >> 1) & 3;
    const int sgc = (gc & ~3) | ((gc & 3) ^ f);      // swizzled source granule
    alignas(16) unsigned short hi[8], lo[8];
    if (m < MROWS) {
        const float* src = hist + (size_t)m * KDIM + sgc * 8;
        float4 a = *(const float4*)(src);
        float4 b = *(const float4*)(src + 4);
        const float v[8] = {a.x, a.y, a.z, a.w, b.x, b.y, b.z, b.w};
#pragma unroll
        for (int i = 0; i < 8; ++i) {
            unsigned short h = f2bf_rne(v[i]);
            hi[i] = h;
            lo[i] = f2bf_rne(v[i] - bf2f(h));        // exact residual (Sterbenz)
        }
    } else {
#pragma unroll
        for (int i = 0; i < 8; ++i) { hi[i] = 0; lo[i] = 0; }
    }
    *(uint4*)(ahi + (size_t)g * 8) = *(const uint4*)hi;
    *(uint4*)(alo + (size_t)g * 8) = *(const uint4*)lo;
}

// ---------------------------------------------------------------------------
// Fused GEMM + bind-reduce, BM=224 x BN=128 x BK=32, SINGLE m-block:
// pos_w (512 MB, the HBM bottleneck) is read exactly once (was 2x).
// A staged via global_load_lds width=16 from prebuilt bf16 planes.
// Grid (KSL, 64): linear id = ks + 16*nb -> XCD = ks%8, so each XCD's A
// working set is 2 k-slices (~1.8 MB) and stays L2-resident.
// 4 waves 2x2: wave covers 112 m (7 frags) x 64 n (4 frags), acc[7][4].
// ---------------------------------------------------------------------------
__global__ __launch_bounds__(256, 2)
void gemm_kernel(const unsigned short* __restrict__ ahi,
                 const unsigned short* __restrict__ alo,
                 const float* __restrict__ pos,
                 const float* __restrict__ time_w,
                 const float* __restrict__ pol_w,
                 float* __restrict__ out) {
    __shared__ alignas(16) unsigned short As0[PM * BK];   // hi plane, 14336 B
    __shared__ alignas(16) unsigned short As1[PM * BK];   // lo plane, 14336 B
    __shared__ alignas(16) unsigned short Bs[128][40];    // [n][k], +8 pad
    __shared__ float sPart[128];

    const int t     = threadIdx.x;
    const int ks    = blockIdx.x;              // k-slice major for XCD grouping
    const int n0    = blockIdx.y * 128;
    const int kbase = ks * KPER;

    const int lane = t & 63;
    const int wv   = t >> 6;
    const int wm   = (wv & 1) * 112;           // 7 frag-rows per wave
    const int wn   = (wv >> 1) * 64;
    const int l15  = lane & 15;
    const int q8   = (lane >> 4) * 8;          // B k-granule offset
    // A granule after de-swizzle; f(m_r) reduces to (l15>>1)&3 because
    // wm/2 (=0,56) and s*8 are both 0 mod 4.
    const int qg   = (lane >> 4) ^ ((l15 >> 1) & 3);

    if (t < 128) sPart[t] = 0.f;

    // A chunk assignment: 28 chunks (2 planes x 14 chunks of 16 rows), 7/wave.
    const int lr = lane >> 2, lg = lane & 3;   // lane -> (row-in-chunk, granule)
    const unsigned short* gA[7];
    unsigned short* lA[7];
#pragma unroll
    for (int i = 0; i < 7; ++i) {
        const int cc = wv * 7 + i;
        const int pl = (cc >= 14) ? 1 : 0;
        const int ch = cc - pl * 14;
        gA[i] = (pl ? alo : ahi) + (size_t)(ch * 16 + lr) * KDIM + kbase + lg * 8;
        lA[i] = (pl ? As1 : As0) + ch * 512;   // wave-uniform LDS base
    }

    // B staging map (unchanged from verified kernel): 2 k-rows x 8 n / thread
    const int bk2 = (t & 15) * 2;
    const int bnb = (t >> 4) * 8;
    const float* gB0 = pos + ((size_t)kbase + bk2) * DDIM + n0 + bnb;
    const float* gB1 = gB0 + DDIM;

    f32x4 acc[7][4];
#pragma unroll
    for (int s = 0; s < 7; ++s)
#pragma unroll
        for (int j = 0; j < 4; ++j) acc[s][j] = (f32x4){0.f, 0.f, 0.f, 0.f};

    for (int kk = 0; kk < KPER; kk += BK) {
        // B global loads first (overlap with prior MFMAs)
        const float* b0 = gB0 + (size_t)kk * DDIM;
        const float* b1 = gB1 + (size_t)kk * DDIM;
        float4 x0 = *(const float4*)(b0);
        float4 x1 = *(const float4*)(b0 + 4);
        float4 y0 = *(const float4*)(b1);
        float4 y1 = *(const float4*)(b1 + 4);

        __syncthreads();                       // prev iter's frag reads done

        // A: async direct-to-LDS (dest linear; source pre-swizzled by prep)
#pragma unroll
        for (int i = 0; i < 7; ++i) gld_lds16(gA[i] + kk, lA[i]);

        // B: truncate fp32 +/-1 -> bf16 (exact), transpose into [n][k]
        {
            const float xv[8] = {x0.x, x0.y, x0.z, x0.w, x1.x, x1.y, x1.z, x1.w};
            const float yv[8] = {y0.x, y0.y, y0.z, y0.w, y1.x, y1.y, y1.z, y1.w};
#pragma unroll
            for (int j = 0; j < 8; ++j) {
                unsigned int w = (__float_as_uint(xv[j]) >> 16) |
                                 (__float_as_uint(yv[j]) & 0xFFFF0000u);
                *(unsigned int*)&Bs[bnb + j][bk2] = w;
            }
        }

        __syncthreads();                       // drains vmcnt (A) + lgkm (B)

        uint4 fb[4];
#pragma unroll
        for (int j = 0; j < 4; ++j)
            fb[j] = *(const uint4*)&Bs[wn + j * 16 + l15][q8];

#pragma unroll
        for (int s = 0; s < 7; ++s) {
            const int mr = wm + s * 16 + l15;
            const uint4 fa0 = *(const uint4*)&As0[mr * 32 + qg * 8];
            const uint4 fa1 = *(const uint4*)&As1[mr * 32 + qg * 8];
#pragma unroll
            for (int j = 0; j < 4; ++j) {
                acc[s][j] = __builtin_amdgcn_mfma_f32_16x16x32_bf16(
                    __builtin_bit_cast(bf16x8, fa0),
                    __builtin_bit_cast(bf16x8, fb[j]), acc[s][j], 0, 0, 0);
                acc[s][j] = __builtin_amdgcn_mfma_f32_16x16x32_bf16(
                    __builtin_bit_cast(bf16x8, fa1),
                    __builtin_bit_cast(bf16x8, fb[j]), acc[s][j], 0, 0, 0);
            }
        }
    }

    // Epilogue: C/D layout col = lane&15, row = (lane>>4)*4 + reg (m89/m91).
    const int qrow = (lane >> 4) * 4;
#pragma unroll
    for (int j = 0; j < 4; ++j) {
        const int col = wn + j * 16 + l15;
        const int d   = n0 + col;
        const float p0 = pol_w[d];
        const float p1 = pol_w[DDIM + d];
        float part = 0.f;
#pragma unroll
        for (int s = 0; s < 7; ++s)
#pragma unroll
            for (int r = 0; r < 4; ++r) {
                const int m = wm + s * 16 + qrow + r;
                if (m < MROWS) {               // pad rows: zero A, skip weights
                    const float w = time_w[(size_t)(m >> 1) * DDIM + d] *
                                    ((m & 1) ? p1 : p0);
                    part += w * acc[s][j][r];
                }
            }
        atomicAdd(&sPart[col], part);
    }
    __syncthreads();
    if (t < 128) atomicAdd(out + n0 + t, sPart[t]);
}

// ---------------------------------------------------------------------------
// Final: out[d] = sign(out[d]) in place.
// ---------------------------------------------------------------------------
__global__ __launch_bounds__(256) void sign_kernel(float* __restrict__ out) {
    int d = blockIdx.x * 256 + threadIdx.x;
    float s = out[d];
    out[d] = (s > 0.f) ? 1.f : ((s < 0.f) ? -1.f : 0.f);
}

// ---------------------------------------------------------------------------
extern "C" void kernel_launch(void* const* d_in, const int* in_sizes, int n_in,
                              void* d_out, int out_size, void* d_ws, size_t ws_size,
                              hipStream_t stream) {
    const float* hist   = (const float*)d_in[0];   // [100,2,128,128]
    const float* time_w = (const float*)d_in[1];   // [100,8192]
    const float* pol_w  = (const float*)d_in[2];   // [2,8192]
    const float* pos_w  = (const float*)d_in[3];   // [16384,8192]
    float* out = (float*)d_out;                    // [8192]

    unsigned short* ahi = (unsigned short*)d_ws;               // 7.34 MB
    unsigned short* alo = ahi + (size_t)PM * KDIM;             // 7.34 MB
    (void)in_sizes; (void)n_in; (void)out_size; (void)ws_size; // ws >= 14.7 MB

    zero_kernel<<<DDIM / 256, 256, 0, stream>>>(out);
    prep_kernel<<<(PM * (KDIM / 8)) / 256, 256, 0, stream>>>(hist, ahi, alo);
    gemm_kernel<<<dim3(KSL, DDIM / 128), 256, 0, stream>>>(ahi, alo, pos_w,
                                                           time_w, pol_w, out);
    sign_kernel<<<DDIM / 256, 256, 0, stream>>>(out);
}